// Round 9
// baseline (2591.770 us; speedup 1.0000x reference)
//
#include <hip/hip_runtime.h>

// Problem constants (fixed by the reference)
#define BATCH 4
#define HH    56
#define WW    56
#define NTOK  3136    // 56*56
#define NKV   784     // 28*28
#define CD    512
#define NH    8
#define DH    64
#define SCALE 0.125f  // (512/8)^-0.5
#define KVHALF 392    // per-wave KV share

// ---------------- workspace layout (floats) ----------------
// Byte-identical to the round-1 run that passed (74.9 MB).
static const size_t OFF_Q   = 0;          // qbuf [12544,512]
static const size_t OFF_SCR = 6422528;    // im2col [3136,2048]; later attn-out [12544,512]
static const size_t OFF_KV  = 12845056;   // conv+LN out [3136,512]
static const size_t OFF_KVP = 14450688;   // kv proj [3136,1024]
static const size_t OFF_SWT = 17661952;   // sr_w transposed [2048,512]

// ---- sr_w OIHW [512,512,2,2] -> [p*512+i][o]  (p = ky*2+kx) ----  [R1-proven]
__global__ void srwt_k(const float* __restrict__ w, float* __restrict__ out) {
    int idx = blockIdx.x * blockDim.x + threadIdx.x;   // over 2048*512
    int o = idx & 511;
    int rest = idx >> 9;
    int i = rest & 511;
    int p = rest >> 9;
    out[idx] = w[(((size_t)o * 512 + i) << 2) + p];
}

// ---- im2col: v [B,3136,512] -> [B*784, 2048] (p-major: p*512+i) ----  [R1-proven]
__global__ void im2col_k(const float* __restrict__ v, float* __restrict__ out) {
    int idx = blockIdx.x * blockDim.x + threadIdx.x;   // over 3136*2048
    int i = idx & 511;
    int p = (idx >> 9) & 3;
    int t = idx >> 11;                 // 0..3135  (b*784 + oy*28+ox)
    int b = t / NKV;
    int tt = t - b * NKV;
    int oy = tt / 28, ox = tt - (tt / 28) * 28;
    int ky = p >> 1, kx = p & 1;
    int y = oy * 2 + ky, x = ox * 2 + kx;
    out[idx] = v[((size_t)b * NTOK + y * WW + x) * CD + i];
}

// ---- generic fp32 GEMM: C[M,N] = A[M,K] @ B[K,N] (+bias[N]) ----  [R1-proven]
// 64x64 tile, BK=16, 256 threads, 4x4 per thread. M%64==0, N%64==0, K%16==0.
__global__ __launch_bounds__(256) void gemm64(
    const float* __restrict__ A, const float* __restrict__ Bm,
    const float* __restrict__ bias, float* __restrict__ C,
    int M, int N, int K)
{
    __shared__ float As[16][68];
    __shared__ float Bs[16][68];
    const int tid = threadIdx.x;
    const int bn = blockIdx.x * 64;
    const int bm = blockIdx.y * 64;
    const int tx = tid & 15, ty = tid >> 4;
    const int la_c = tid & 15, la_r = tid >> 4;   // A tile: col k, row
    const int lb_c = tid & 63, lb_r = tid >> 6;   // B tile
    float acc[4][4] = {};
    for (int k0 = 0; k0 < K; k0 += 16) {
        #pragma unroll
        for (int r = 0; r < 4; ++r)
            As[la_c][la_r + 16 * r] = A[(size_t)(bm + la_r + 16 * r) * K + k0 + la_c];
        #pragma unroll
        for (int r = 0; r < 4; ++r)
            Bs[lb_r + 4 * r][lb_c] = Bm[(size_t)(k0 + lb_r + 4 * r) * N + bn + lb_c];
        __syncthreads();
        #pragma unroll
        for (int kk = 0; kk < 16; ++kk) {
            float4 av = *(const float4*)&As[kk][ty * 4];
            float4 bv = *(const float4*)&Bs[kk][tx * 4];
            float a[4] = {av.x, av.y, av.z, av.w};
            float b[4] = {bv.x, bv.y, bv.z, bv.w};
            #pragma unroll
            for (int i = 0; i < 4; ++i)
                #pragma unroll
                for (int j = 0; j < 4; ++j)
                    acc[i][j] = fmaf(a[i], b[j], acc[i][j]);
        }
        __syncthreads();
    }
    #pragma unroll
    for (int i = 0; i < 4; ++i) {
        int row = bm + ty * 4 + i;
        int col = bn + tx * 4;
        float b0 = bias ? bias[col + 0] : 0.f;
        float b1 = bias ? bias[col + 1] : 0.f;
        float b2 = bias ? bias[col + 2] : 0.f;
        float b3 = bias ? bias[col + 3] : 0.f;
        float4 o = make_float4(acc[i][0] + b0, acc[i][1] + b1,
                               acc[i][2] + b2, acc[i][3] + b3);
        *(float4*)&C[(size_t)row * N + col] = o;
    }
}

// ---- LayerNorm over 512, in place. One block (256 thr) per token. ----  [R1-proven]
__global__ __launch_bounds__(256) void ln_k(float* __restrict__ x,
    const float* __restrict__ g, const float* __restrict__ bta)
{
    int t = blockIdx.x;
    float* row = x + (size_t)t * CD;
    int tid = threadIdx.x;
    float2 xv = *(float2*)&row[tid * 2];
    float s  = xv.x + xv.y;
    float s2 = xv.x * xv.x + xv.y * xv.y;
    #pragma unroll
    for (int off = 32; off > 0; off >>= 1) {
        s  += __shfl_down(s, off);
        s2 += __shfl_down(s2, off);
    }
    __shared__ float sa[4], sb[4];
    int wid = tid >> 6, lane = tid & 63;
    if (lane == 0) { sa[wid] = s; sb[wid] = s2; }
    __syncthreads();
    if (tid == 0) {
        float S = sa[0] + sa[1] + sa[2] + sa[3];
        float S2 = sb[0] + sb[1] + sb[2] + sb[3];
        sa[0] = S; sb[0] = S2;
    }
    __syncthreads();
    float mu  = sa[0] * (1.f / 512.f);
    float var = sb[0] * (1.f / 512.f) - mu * mu;
    float inv = rsqrtf(var + 1e-5f);
    float2 gv = *(const float2*)&g[tid * 2];
    float2 bv = *(const float2*)&bta[tid * 2];
    xv.x = (xv.x - mu) * inv * gv.x + bv.x;
    xv.y = (xv.y - mu) * inv * gv.y + bv.y;
    *(float2*)&row[tid * 2] = xv;
}

// ---- attention: 2 waves/block, each wave does half the KV tokens; ----  [NEW]
// ---- combine via LDS. No staging LDS; K/V read wave-uniform from L2. ----
__global__ __launch_bounds__(128, 3) void attn2w(
    const float* __restrict__ q, const float* __restrict__ kvp,
    float* __restrict__ out)
{
    __shared__ float Pacc[64][68];
    __shared__ float Pden[64];
    const int qb = blockIdx.x;    // 0..48
    const int h  = blockIdx.y;    // 0..7
    const int b  = blockIdx.z;    // 0..3
    const int tid = threadIdx.x;
    const int lane = tid & 63, wv = tid >> 6;
    const int r = qb * 64 + lane;
    const float* qrow = q + ((size_t)(b * NTOK + r)) * CD + h * DH;
    float qr[64];
    #pragma unroll
    for (int d4 = 0; d4 < 16; ++d4) {
        float4 t = *(const float4*)&qrow[d4 * 4];
        qr[d4*4+0] = t.x; qr[d4*4+1] = t.y; qr[d4*4+2] = t.z; qr[d4*4+3] = t.w;
    }
    float acc[64];
    #pragma unroll
    for (int d = 0; d < 64; ++d) acc[d] = 0.f;
    float denom = 0.f;
    const float* kbase = kvp + ((size_t)(b * NKV + wv * KVHALF)) * 1024 + h * DH;
    for (int j = 0; j < KVHALF; ++j) {
        const float* kp = kbase + (size_t)j * 1024;   // wave-uniform address
        float p0 = 0.f, p1 = 0.f, p2 = 0.f, p3 = 0.f;
        #pragma unroll
        for (int d4 = 0; d4 < 16; ++d4) {
            float4 k4 = *(const float4*)&kp[d4 * 4];
            p0 = fmaf(qr[d4*4+0], k4.x, p0);
            p1 = fmaf(qr[d4*4+1], k4.y, p1);
            p2 = fmaf(qr[d4*4+2], k4.z, p2);
            p3 = fmaf(qr[d4*4+3], k4.w, p3);
        }
        float p = __expf(((p0 + p1) + (p2 + p3)) * SCALE);
        denom += p;
        #pragma unroll
        for (int d4 = 0; d4 < 16; ++d4) {
            float4 v4 = *(const float4*)&kp[512 + d4 * 4];
            acc[d4*4+0] = fmaf(p, v4.x, acc[d4*4+0]);
            acc[d4*4+1] = fmaf(p, v4.y, acc[d4*4+1]);
            acc[d4*4+2] = fmaf(p, v4.z, acc[d4*4+2]);
            acc[d4*4+3] = fmaf(p, v4.w, acc[d4*4+3]);
        }
    }
    if (wv == 1) {
        #pragma unroll
        for (int d4 = 0; d4 < 16; ++d4)
            *(float4*)&Pacc[lane][d4 * 4] =
                make_float4(acc[d4*4+0], acc[d4*4+1], acc[d4*4+2], acc[d4*4+3]);
        Pden[lane] = denom;
    }
    __syncthreads();
    if (wv == 0) {
        float inv = 1.f / (denom + Pden[lane]);
        float* op = out + ((size_t)(b * NTOK + r)) * CD + h * DH;
        #pragma unroll
        for (int d4 = 0; d4 < 16; ++d4) {
            float4 o2 = *(const float4*)&Pacc[lane][d4 * 4];
            *(float4*)&op[d4 * 4] = make_float4(
                (acc[d4*4+0] + o2.x) * inv, (acc[d4*4+1] + o2.y) * inv,
                (acc[d4*4+2] + o2.z) * inv, (acc[d4*4+3] + o2.w) * inv);
        }
    }
}

extern "C" void kernel_launch(void* const* d_in, const int* in_sizes, int n_in,
                              void* d_out, int out_size, void* d_ws, size_t ws_size,
                              hipStream_t stream)
{
    const float* x    = (const float*)d_in[0];
    const float* v    = (const float*)d_in[1];
    // d_in[2], d_in[3] are h,w scalars (fixed 56x56 — compiled in)
    const float* q_w  = (const float*)d_in[4];
    const float* kv_w = (const float*)d_in[5];
    const float* sr_w = (const float*)d_in[6];
    const float* sr_b = (const float*)d_in[7];
    const float* ln_g = (const float*)d_in[8];
    const float* ln_b = (const float*)d_in[9];
    const float* pj_w = (const float*)d_in[10];
    const float* pj_b = (const float*)d_in[11];
    float* out = (float*)d_out;
    float* ws  = (float*)d_ws;

    float* qbuf = ws + OFF_Q;
    float* scr  = ws + OFF_SCR;   // im2col, later attention output
    float* kvb  = ws + OFF_KV;
    float* kvp  = ws + OFF_KVP;
    float* swt  = ws + OFF_SWT;

    // 1) transpose sr_w -> [2048, 512]
    srwt_k<<<(2048 * 512) / 256, 256, 0, stream>>>(sr_w, swt);
    // 2) im2col of v -> [3136, 2048]
    im2col_k<<<(3136 * 2048) / 256, 256, 0, stream>>>(v, scr);
    // 3) SR conv as GEMM (+bias): [3136,2048]@[2048,512] -> kvb
    gemm64<<<dim3(8, 49), 256, 0, stream>>>(scr, swt, sr_b, kvb, 3136, 512, 2048);
    // 4) LayerNorm in place
    ln_k<<<3136, 256, 0, stream>>>(kvb, ln_g, ln_b);
    // 5) kv projection: [3136,512]@[512,1024] -> kvp (k | v)
    gemm64<<<dim3(16, 49), 256, 0, stream>>>(kvb, kv_w, nullptr, kvp, 3136, 1024, 512);
    // 6) q projection: [12544,512]@[512,512] -> qbuf
    gemm64<<<dim3(8, 196), 256, 0, stream>>>(x, q_w, nullptr, qbuf, 12544, 512, 512);
    // 7) attention (2-wave blocks, in-block KV split) -> scr
    attn2w<<<dim3(49, 8, 4), 128, 0, stream>>>(qbuf, kvp, scr);
    // 8) output projection (+bias): [12544,512]@[512,512] -> out
    gemm64<<<dim3(8, 196), 256, 0, stream>>>(scr, pj_w, pj_b, out, 12544, 512, 512);
}

// Round 10
// 1390.536 us; speedup vs baseline: 1.8639x; 1.8639x over previous
//
#include <hip/hip_runtime.h>

// Problem constants (fixed by the reference)
#define BATCH 4
#define HH    56
#define WW    56
#define NTOK  3136    // 56*56
#define NKV   784     // 28*28
#define CD    512
#define NH    8
#define DH    64
#define SCALE 0.125f  // (512/8)^-0.5
#define KVHALF 392    // per-wave KV share
#define CHUNK 14      // kv tokens staged per iteration (392 = 28*14)

// ---------------- workspace layout (floats) ----------------
// Byte-identical to the round-1/round-9 runs that passed (74.9 MB).
static const size_t OFF_Q   = 0;          // qbuf [12544,512]
static const size_t OFF_SCR = 6422528;    // im2col [3136,2048]; later attn-out [12544,512]
static const size_t OFF_KV  = 12845056;   // conv+LN out [3136,512]
static const size_t OFF_KVP = 14450688;   // kv proj [3136,1024]
static const size_t OFF_SWT = 17661952;   // sr_w transposed [2048,512]

// ---- sr_w OIHW [512,512,2,2] -> [p*512+i][o]  (p = ky*2+kx) ----  [R1-proven]
__global__ void srwt_k(const float* __restrict__ w, float* __restrict__ out) {
    int idx = blockIdx.x * blockDim.x + threadIdx.x;   // over 2048*512
    int o = idx & 511;
    int rest = idx >> 9;
    int i = rest & 511;
    int p = rest >> 9;
    out[idx] = w[(((size_t)o * 512 + i) << 2) + p];
}

// ---- im2col: v [B,3136,512] -> [B*784, 2048] (p-major: p*512+i) ----  [R1-proven]
__global__ void im2col_k(const float* __restrict__ v, float* __restrict__ out) {
    int idx = blockIdx.x * blockDim.x + threadIdx.x;   // over 3136*2048
    int i = idx & 511;
    int p = (idx >> 9) & 3;
    int t = idx >> 11;                 // 0..3135  (b*784 + oy*28+ox)
    int b = t / NKV;
    int tt = t - b * NKV;
    int oy = tt / 28, ox = tt - (tt / 28) * 28;
    int ky = p >> 1, kx = p & 1;
    int y = oy * 2 + ky, x = ox * 2 + kx;
    out[idx] = v[((size_t)b * NTOK + y * WW + x) * CD + i];
}

// ---- generic fp32 GEMM: C[M,N] = A[M,K] @ B[K,N] (+bias[N]) ----  [R1-proven]
// 64x64 tile, BK=16, 256 threads, 4x4 per thread. M%64==0, N%64==0, K%16==0.
__global__ __launch_bounds__(256) void gemm64(
    const float* __restrict__ A, const float* __restrict__ Bm,
    const float* __restrict__ bias, float* __restrict__ C,
    int M, int N, int K)
{
    __shared__ float As[16][68];
    __shared__ float Bs[16][68];
    const int tid = threadIdx.x;
    const int bn = blockIdx.x * 64;
    const int bm = blockIdx.y * 64;
    const int tx = tid & 15, ty = tid >> 4;
    const int la_c = tid & 15, la_r = tid >> 4;   // A tile: col k, row
    const int lb_c = tid & 63, lb_r = tid >> 6;   // B tile
    float acc[4][4] = {};
    for (int k0 = 0; k0 < K; k0 += 16) {
        #pragma unroll
        for (int r = 0; r < 4; ++r)
            As[la_c][la_r + 16 * r] = A[(size_t)(bm + la_r + 16 * r) * K + k0 + la_c];
        #pragma unroll
        for (int r = 0; r < 4; ++r)
            Bs[lb_r + 4 * r][lb_c] = Bm[(size_t)(k0 + lb_r + 4 * r) * N + bn + lb_c];
        __syncthreads();
        #pragma unroll
        for (int kk = 0; kk < 16; ++kk) {
            float4 av = *(const float4*)&As[kk][ty * 4];
            float4 bv = *(const float4*)&Bs[kk][tx * 4];
            float a[4] = {av.x, av.y, av.z, av.w};
            float b[4] = {bv.x, bv.y, bv.z, bv.w};
            #pragma unroll
            for (int i = 0; i < 4; ++i)
                #pragma unroll
                for (int j = 0; j < 4; ++j)
                    acc[i][j] = fmaf(a[i], b[j], acc[i][j]);
        }
        __syncthreads();
    }
    #pragma unroll
    for (int i = 0; i < 4; ++i) {
        int row = bm + ty * 4 + i;
        int col = bn + tx * 4;
        float b0 = bias ? bias[col + 0] : 0.f;
        float b1 = bias ? bias[col + 1] : 0.f;
        float b2 = bias ? bias[col + 2] : 0.f;
        float b3 = bias ? bias[col + 3] : 0.f;
        float4 o = make_float4(acc[i][0] + b0, acc[i][1] + b1,
                               acc[i][2] + b2, acc[i][3] + b3);
        *(float4*)&C[(size_t)row * N + col] = o;
    }
}

// ---- LayerNorm over 512, in place. One block (256 thr) per token. ----  [R1-proven]
__global__ __launch_bounds__(256) void ln_k(float* __restrict__ x,
    const float* __restrict__ g, const float* __restrict__ bta)
{
    int t = blockIdx.x;
    float* row = x + (size_t)t * CD;
    int tid = threadIdx.x;
    float2 xv = *(float2*)&row[tid * 2];
    float s  = xv.x + xv.y;
    float s2 = xv.x * xv.x + xv.y * xv.y;
    #pragma unroll
    for (int off = 32; off > 0; off >>= 1) {
        s  += __shfl_down(s, off);
        s2 += __shfl_down(s2, off);
    }
    __shared__ float sa[4], sb[4];
    int wid = tid >> 6, lane = tid & 63;
    if (lane == 0) { sa[wid] = s; sb[wid] = s2; }
    __syncthreads();
    if (tid == 0) {
        float S = sa[0] + sa[1] + sa[2] + sa[3];
        float S2 = sb[0] + sb[1] + sb[2] + sb[3];
        sa[0] = S; sb[0] = S2;
    }
    __syncthreads();
    float mu  = sa[0] * (1.f / 512.f);
    float var = sb[0] * (1.f / 512.f) - mu * mu;
    float inv = rsqrtf(var + 1e-5f);
    float2 gv = *(const float2*)&g[tid * 2];
    float2 bv = *(const float2*)&bta[tid * 2];
    xv.x = (xv.x - mu) * inv * gv.x + bv.x;
    xv.y = (xv.y - mu) * inv * gv.y + bv.y;
    *(float2*)&row[tid * 2] = xv;
}

// ---- attention v3: 2 waves/block, KV split 392+392, LDS-staged chunks. ---- [NEW]
// Fix for attn2w's latency collapse (R9: VALUBusy 11%): wave-uniform global
// K/V reads got scalarized -> serialized on the scalar cache. Now each wave
// stages CHUNK=14 tokens into ITS OWN LDS buffer with per-lane coalesced
// vector loads (no barrier needed), inner loop reads LDS via broadcast.
// Staging layout token-major stride 68: b128 writes 2-way bank-aliased (free),
// broadcast reads conflict-free. Combine buffer overlays the staging area.
__global__ __launch_bounds__(128, 3) void attn3(
    const float* __restrict__ q, const float* __restrict__ kvp,
    float* __restrict__ out)
{
    __shared__ __align__(16) float lds[4480];   // 17.9 KB
    const int qb = blockIdx.x;    // 0..48
    const int h  = blockIdx.y;    // 0..7
    const int b  = blockIdx.z;    // 0..3
    const int tid = threadIdx.x;
    const int lane = tid & 63, wv = tid >> 6;
    const int r = qb * 64 + lane;
    const float* qrow = q + ((size_t)(b * NTOK + r)) * CD + h * DH;
    float qr[64];
    #pragma unroll
    for (int d4 = 0; d4 < 16; ++d4) {
        float4 t = *(const float4*)&qrow[d4 * 4];
        qr[d4*4+0] = t.x; qr[d4*4+1] = t.y; qr[d4*4+2] = t.z; qr[d4*4+3] = t.w;
    }
    float acc[64];
    #pragma unroll
    for (int d = 0; d < 64; ++d) acc[d] = 0.f;
    float denom = 0.f;
    // wave-private staging: K [14][68] then V [14][68]
    float* Kl = lds + wv * 1904;
    const float* kvbase = kvp + ((size_t)(b * NKV + wv * KVHALF)) * 1024 + h * DH;
    // per-lane slot decomposition (constant across chunks)
    const int s_tok  = lane >> 5;            // 0..1  (+2 per iter)
    const int s_sub  = lane & 31;
    const int s_kind = s_sub >> 4;           // 0=K, 1=V
    const int s_part = s_sub & 15;           // float4 index within 64 floats
    const int ldst   = s_kind * 952 + s_tok * 68 + s_part * 4;  // + tok2*2*68
    const size_t gost = (size_t)s_tok * 1024 + s_kind * 512 + s_part * 4;

    for (int c0 = 0; c0 < KVHALF; c0 += CHUNK) {
        const float* gsrc = kvbase + (size_t)c0 * 1024;
        #pragma unroll
        for (int it = 0; it < 7; ++it) {     // 7*64 lanes = 448 float4 = 14 tokens K+V
            float4 t = *(const float4*)&gsrc[gost + (size_t)(it * 2) * 1024];
            *(float4*)&Kl[ldst + it * 2 * 68] = t;
        }
        #pragma unroll 2
        for (int j = 0; j < CHUNK; ++j) {
            const float* kj = &Kl[j * 68];
            float p0 = 0.f, p1 = 0.f, p2 = 0.f, p3 = 0.f;
            #pragma unroll
            for (int d4 = 0; d4 < 16; ++d4) {
                float4 k4 = *(const float4*)&kj[d4 * 4];
                p0 = fmaf(qr[d4*4+0], k4.x, p0);
                p1 = fmaf(qr[d4*4+1], k4.y, p1);
                p2 = fmaf(qr[d4*4+2], k4.z, p2);
                p3 = fmaf(qr[d4*4+3], k4.w, p3);
            }
            float p = __expf(((p0 + p1) + (p2 + p3)) * SCALE);
            denom += p;
            const float* vj = &kj[952];
            #pragma unroll
            for (int d4 = 0; d4 < 16; ++d4) {
                float4 v4 = *(const float4*)&vj[d4 * 4];
                acc[d4*4+0] = fmaf(p, v4.x, acc[d4*4+0]);
                acc[d4*4+1] = fmaf(p, v4.y, acc[d4*4+1]);
                acc[d4*4+2] = fmaf(p, v4.z, acc[d4*4+2]);
                acc[d4*4+3] = fmaf(p, v4.w, acc[d4*4+3]);
            }
        }
    }
    __syncthreads();                 // both waves done with staging areas
    // overlay: Pacc [64][68] at lds[0..4351], Pden at lds[4352..4415]
    float* Pacc = lds;
    float* Pden = lds + 4352;
    if (wv == 1) {
        #pragma unroll
        for (int d4 = 0; d4 < 16; ++d4)
            *(float4*)&Pacc[lane * 68 + d4 * 4] =
                make_float4(acc[d4*4+0], acc[d4*4+1], acc[d4*4+2], acc[d4*4+3]);
        Pden[lane] = denom;
    }
    __syncthreads();
    if (wv == 0) {
        float inv = 1.f / (denom + Pden[lane]);
        float* op = out + ((size_t)(b * NTOK + r)) * CD + h * DH;
        #pragma unroll
        for (int d4 = 0; d4 < 16; ++d4) {
            float4 o2 = *(const float4*)&Pacc[lane * 68 + d4 * 4];
            *(float4*)&op[d4 * 4] = make_float4(
                (acc[d4*4+0] + o2.x) * inv, (acc[d4*4+1] + o2.y) * inv,
                (acc[d4*4+2] + o2.z) * inv, (acc[d4*4+3] + o2.w) * inv);
        }
    }
}

extern "C" void kernel_launch(void* const* d_in, const int* in_sizes, int n_in,
                              void* d_out, int out_size, void* d_ws, size_t ws_size,
                              hipStream_t stream)
{
    const float* x    = (const float*)d_in[0];
    const float* v    = (const float*)d_in[1];
    // d_in[2], d_in[3] are h,w scalars (fixed 56x56 — compiled in)
    const float* q_w  = (const float*)d_in[4];
    const float* kv_w = (const float*)d_in[5];
    const float* sr_w = (const float*)d_in[6];
    const float* sr_b = (const float*)d_in[7];
    const float* ln_g = (const float*)d_in[8];
    const float* ln_b = (const float*)d_in[9];
    const float* pj_w = (const float*)d_in[10];
    const float* pj_b = (const float*)d_in[11];
    float* out = (float*)d_out;
    float* ws  = (float*)d_ws;

    float* qbuf = ws + OFF_Q;
    float* scr  = ws + OFF_SCR;   // im2col, later attention output
    float* kvb  = ws + OFF_KV;
    float* kvp  = ws + OFF_KVP;
    float* swt  = ws + OFF_SWT;

    // 1) transpose sr_w -> [2048, 512]
    srwt_k<<<(2048 * 512) / 256, 256, 0, stream>>>(sr_w, swt);
    // 2) im2col of v -> [3136, 2048]
    im2col_k<<<(3136 * 2048) / 256, 256, 0, stream>>>(v, scr);
    // 3) SR conv as GEMM (+bias): [3136,2048]@[2048,512] -> kvb
    gemm64<<<dim3(8, 49), 256, 0, stream>>>(scr, swt, sr_b, kvb, 3136, 512, 2048);
    // 4) LayerNorm in place
    ln_k<<<3136, 256, 0, stream>>>(kvb, ln_g, ln_b);
    // 5) kv projection: [3136,512]@[512,1024] -> kvp (k | v)
    gemm64<<<dim3(16, 49), 256, 0, stream>>>(kvb, kv_w, nullptr, kvp, 3136, 1024, 512);
    // 6) q projection: [12544,512]@[512,512] -> qbuf
    gemm64<<<dim3(8, 196), 256, 0, stream>>>(x, q_w, nullptr, qbuf, 12544, 512, 512);
    // 7) attention v3 (LDS-staged, 2-wave KV split) -> scr
    attn3<<<dim3(49, 8, 4), 128, 0, stream>>>(qbuf, kvp, scr);
    // 8) output projection (+bias): [12544,512]@[512,512] -> out
    gemm64<<<dim3(8, 196), 256, 0, stream>>>(scr, pj_w, pj_b, out, 12544, 512, 512);
}

// Round 14
// 1300.512 us; speedup vs baseline: 1.9929x; 1.0692x over previous
//
#include <hip/hip_runtime.h>

// Problem constants (fixed by the reference)
#define BATCH 4
#define HH    56
#define WW    56
#define NTOK  3136    // 56*56
#define NKV   784     // 28*28
#define CD    512
#define NH    8
#define DH    64
#define SCALE 0.125f  // (512/8)^-0.5
#define KVHALF 392    // per-wave KV share
#define CHUNK 14      // kv tokens staged per iteration (392 = 28*14)

// ---------------- workspace layout (floats) ----------------
// Byte-identical to the round-1/round-9/round-10 runs that passed (74.9 MB).
static const size_t OFF_Q   = 0;          // qbuf [12544,512]
static const size_t OFF_SCR = 6422528;    // im2col [3136,2048]; later attn-out [12544,512]
static const size_t OFF_KV  = 12845056;   // conv+LN out [3136,512]
static const size_t OFF_KVP = 14450688;   // kv proj [3136,1024]
static const size_t OFF_SWT = 17661952;   // sr_w transposed [2048,512]

// ---- sr_w OIHW [512,512,2,2] -> [p*512+i][o]  (p = ky*2+kx) ----  [R1-proven]
__global__ void srwt_k(const float* __restrict__ w, float* __restrict__ out) {
    int idx = blockIdx.x * blockDim.x + threadIdx.x;   // over 2048*512
    int o = idx & 511;
    int rest = idx >> 9;
    int i = rest & 511;
    int p = rest >> 9;
    out[idx] = w[(((size_t)o * 512 + i) << 2) + p];
}

// ---- im2col: v [B,3136,512] -> [B*784, 2048] (p-major: p*512+i) ----  [R1-proven]
__global__ void im2col_k(const float* __restrict__ v, float* __restrict__ out) {
    int idx = blockIdx.x * blockDim.x + threadIdx.x;   // over 3136*2048
    int i = idx & 511;
    int p = (idx >> 9) & 3;
    int t = idx >> 11;                 // 0..3135  (b*784 + oy*28+ox)
    int b = t / NKV;
    int tt = t - b * NKV;
    int oy = tt / 28, ox = tt - (tt / 28) * 28;
    int ky = p >> 1, kx = p & 1;
    int y = oy * 2 + ky, x = ox * 2 + kx;
    out[idx] = v[((size_t)b * NTOK + y * WW + x) * CD + i];
}

// ---- generic fp32 GEMM: C[M,N] = A[M,K] @ B[K,N] (+bias[N]) ----  [R1-proven]
// 64x64 tile, BK=16, 256 threads, 4x4 per thread. M%64==0, N%64==0, K%16==0.
__global__ __launch_bounds__(256) void gemm64(
    const float* __restrict__ A, const float* __restrict__ Bm,
    const float* __restrict__ bias, float* __restrict__ C,
    int M, int N, int K)
{
    __shared__ float As[16][68];
    __shared__ float Bs[16][68];
    const int tid = threadIdx.x;
    const int bn = blockIdx.x * 64;
    const int bm = blockIdx.y * 64;
    const int tx = tid & 15, ty = tid >> 4;
    const int la_c = tid & 15, la_r = tid >> 4;   // A tile: col k, row
    const int lb_c = tid & 63, lb_r = tid >> 6;   // B tile
    float acc[4][4] = {};
    for (int k0 = 0; k0 < K; k0 += 16) {
        #pragma unroll
        for (int r = 0; r < 4; ++r)
            As[la_c][la_r + 16 * r] = A[(size_t)(bm + la_r + 16 * r) * K + k0 + la_c];
        #pragma unroll
        for (int r = 0; r < 4; ++r)
            Bs[lb_r + 4 * r][lb_c] = Bm[(size_t)(k0 + lb_r + 4 * r) * N + bn + lb_c];
        __syncthreads();
        #pragma unroll
        for (int kk = 0; kk < 16; ++kk) {
            float4 av = *(const float4*)&As[kk][ty * 4];
            float4 bv = *(const float4*)&Bs[kk][tx * 4];
            float a[4] = {av.x, av.y, av.z, av.w};
            float b[4] = {bv.x, bv.y, bv.z, bv.w};
            #pragma unroll
            for (int i = 0; i < 4; ++i)
                #pragma unroll
                for (int j = 0; j < 4; ++j)
                    acc[i][j] = fmaf(a[i], b[j], acc[i][j]);
        }
        __syncthreads();
    }
    #pragma unroll
    for (int i = 0; i < 4; ++i) {
        int row = bm + ty * 4 + i;
        int col = bn + tx * 4;
        float b0 = bias ? bias[col + 0] : 0.f;
        float b1 = bias ? bias[col + 1] : 0.f;
        float b2 = bias ? bias[col + 2] : 0.f;
        float b3 = bias ? bias[col + 3] : 0.f;
        float4 o = make_float4(acc[i][0] + b0, acc[i][1] + b1,
                               acc[i][2] + b2, acc[i][3] + b3);
        *(float4*)&C[(size_t)row * N + col] = o;
    }
}

// ---- LayerNorm over 512, in place. One block (256 thr) per token. ----  [R1-proven]
__global__ __launch_bounds__(256) void ln_k(float* __restrict__ x,
    const float* __restrict__ g, const float* __restrict__ bta)
{
    int t = blockIdx.x;
    float* row = x + (size_t)t * CD;
    int tid = threadIdx.x;
    float2 xv = *(float2*)&row[tid * 2];
    float s  = xv.x + xv.y;
    float s2 = xv.x * xv.x + xv.y * xv.y;
    #pragma unroll
    for (int off = 32; off > 0; off >>= 1) {
        s  += __shfl_down(s, off);
        s2 += __shfl_down(s2, off);
    }
    __shared__ float sa[4], sb[4];
    int wid = tid >> 6, lane = tid & 63;
    if (lane == 0) { sa[wid] = s; sb[wid] = s2; }
    __syncthreads();
    if (tid == 0) {
        float S = sa[0] + sa[1] + sa[2] + sa[3];
        float S2 = sb[0] + sb[1] + sb[2] + sb[3];
        sa[0] = S; sb[0] = S2;
    }
    __syncthreads();
    float mu  = sa[0] * (1.f / 512.f);
    float var = sb[0] * (1.f / 512.f) - mu * mu;
    float inv = rsqrtf(var + 1e-5f);
    float2 gv = *(const float2*)&g[tid * 2];
    float2 bv = *(const float2*)&bta[tid * 2];
    xv.x = (xv.x - mu) * inv * gv.x + bv.x;
    xv.y = (xv.y - mu) * inv * gv.y + bv.y;
    *(float2*)&row[tid * 2] = xv;
}

// ---- attention v4: attn3 minus the VGPR clamp. ----
// R10 diagnosis: __launch_bounds__(128,3) acted as 3 workgroups/EU = 6
// waves/EU -> VGPR cap 512/6 = 85 (observed 84) -> qr[64]+acc[64] spilled
// to scratch (WRITE_SIZE 172 MB vs 26 MB output). Plain (128) lets the
// compiler allocate ~140 VGPR -> 3 waves/SIMD naturally (512/140), which
// matches the grid's 12.25 waves/CU. Everything else identical to attn3.
__global__ __launch_bounds__(128) void attn4(
    const float* __restrict__ q, const float* __restrict__ kvp,
    float* __restrict__ out)
{
    __shared__ __align__(16) float lds[4480];   // 17.9 KB
    const int qb = blockIdx.x;    // 0..48
    const int h  = blockIdx.y;    // 0..7
    const int b  = blockIdx.z;    // 0..3
    const int tid = threadIdx.x;
    const int lane = tid & 63, wv = tid >> 6;
    const int r = qb * 64 + lane;
    const float* qrow = q + ((size_t)(b * NTOK + r)) * CD + h * DH;
    float qr[64];
    #pragma unroll
    for (int d4 = 0; d4 < 16; ++d4) {
        float4 t = *(const float4*)&qrow[d4 * 4];
        qr[d4*4+0] = t.x; qr[d4*4+1] = t.y; qr[d4*4+2] = t.z; qr[d4*4+3] = t.w;
    }
    float acc[64];
    #pragma unroll
    for (int d = 0; d < 64; ++d) acc[d] = 0.f;
    float denom = 0.f;
    // wave-private staging: K [14][68] then V [14][68]
    float* Kl = lds + wv * 1904;
    const float* kvbase = kvp + ((size_t)(b * NKV + wv * KVHALF)) * 1024 + h * DH;
    // per-lane slot decomposition (constant across chunks)
    const int s_tok  = lane >> 5;            // 0..1  (+2 per iter)
    const int s_sub  = lane & 31;
    const int s_kind = s_sub >> 4;           // 0=K, 1=V
    const int s_part = s_sub & 15;           // float4 index within 64 floats
    const int ldst   = s_kind * 952 + s_tok * 68 + s_part * 4;  // + tok2*2*68
    const size_t gost = (size_t)s_tok * 1024 + s_kind * 512 + s_part * 4;

    for (int c0 = 0; c0 < KVHALF; c0 += CHUNK) {
        const float* gsrc = kvbase + (size_t)c0 * 1024;
        #pragma unroll
        for (int it = 0; it < 7; ++it) {     // 7*64 lanes = 448 float4 = 14 tokens K+V
            float4 t = *(const float4*)&gsrc[gost + (size_t)(it * 2) * 1024];
            *(float4*)&Kl[ldst + it * 2 * 68] = t;
        }
        #pragma unroll 2
        for (int j = 0; j < CHUNK; ++j) {
            const float* kj = &Kl[j * 68];
            float p0 = 0.f, p1 = 0.f, p2 = 0.f, p3 = 0.f;
            #pragma unroll
            for (int d4 = 0; d4 < 16; ++d4) {
                float4 k4 = *(const float4*)&kj[d4 * 4];
                p0 = fmaf(qr[d4*4+0], k4.x, p0);
                p1 = fmaf(qr[d4*4+1], k4.y, p1);
                p2 = fmaf(qr[d4*4+2], k4.z, p2);
                p3 = fmaf(qr[d4*4+3], k4.w, p3);
            }
            float p = __expf(((p0 + p1) + (p2 + p3)) * SCALE);
            denom += p;
            const float* vj = &kj[952];
            #pragma unroll
            for (int d4 = 0; d4 < 16; ++d4) {
                float4 v4 = *(const float4*)&vj[d4 * 4];
                acc[d4*4+0] = fmaf(p, v4.x, acc[d4*4+0]);
                acc[d4*4+1] = fmaf(p, v4.y, acc[d4*4+1]);
                acc[d4*4+2] = fmaf(p, v4.z, acc[d4*4+2]);
                acc[d4*4+3] = fmaf(p, v4.w, acc[d4*4+3]);
            }
        }
    }
    __syncthreads();                 // both waves done with staging areas
    // overlay: Pacc [64][68] at lds[0..4351], Pden at lds[4352..4415]
    float* Pacc = lds;
    float* Pden = lds + 4352;
    if (wv == 1) {
        #pragma unroll
        for (int d4 = 0; d4 < 16; ++d4)
            *(float4*)&Pacc[lane * 68 + d4 * 4] =
                make_float4(acc[d4*4+0], acc[d4*4+1], acc[d4*4+2], acc[d4*4+3]);
        Pden[lane] = denom;
    }
    __syncthreads();
    if (wv == 0) {
        float inv = 1.f / (denom + Pden[lane]);
        float* op = out + ((size_t)(b * NTOK + r)) * CD + h * DH;
        #pragma unroll
        for (int d4 = 0; d4 < 16; ++d4) {
            float4 o2 = *(const float4*)&Pacc[lane * 68 + d4 * 4];
            *(float4*)&op[d4 * 4] = make_float4(
                (acc[d4*4+0] + o2.x) * inv, (acc[d4*4+1] + o2.y) * inv,
                (acc[d4*4+2] + o2.z) * inv, (acc[d4*4+3] + o2.w) * inv);
        }
    }
}

extern "C" void kernel_launch(void* const* d_in, const int* in_sizes, int n_in,
                              void* d_out, int out_size, void* d_ws, size_t ws_size,
                              hipStream_t stream)
{
    const float* x    = (const float*)d_in[0];
    const float* v    = (const float*)d_in[1];
    // d_in[2], d_in[3] are h,w scalars (fixed 56x56 — compiled in)
    const float* q_w  = (const float*)d_in[4];
    const float* kv_w = (const float*)d_in[5];
    const float* sr_w = (const float*)d_in[6];
    const float* sr_b = (const float*)d_in[7];
    const float* ln_g = (const float*)d_in[8];
    const float* ln_b = (const float*)d_in[9];
    const float* pj_w = (const float*)d_in[10];
    const float* pj_b = (const float*)d_in[11];
    float* out = (float*)d_out;
    float* ws  = (float*)d_ws;

    float* qbuf = ws + OFF_Q;
    float* scr  = ws + OFF_SCR;   // im2col, later attention output
    float* kvb  = ws + OFF_KV;
    float* kvp  = ws + OFF_KVP;
    float* swt  = ws + OFF_SWT;

    // 1) transpose sr_w -> [2048, 512]
    srwt_k<<<(2048 * 512) / 256, 256, 0, stream>>>(sr_w, swt);
    // 2) im2col of v -> [3136, 2048]
    im2col_k<<<(3136 * 2048) / 256, 256, 0, stream>>>(v, scr);
    // 3) SR conv as GEMM (+bias): [3136,2048]@[2048,512] -> kvb
    gemm64<<<dim3(8, 49), 256, 0, stream>>>(scr, swt, sr_b, kvb, 3136, 512, 2048);
    // 4) LayerNorm in place
    ln_k<<<3136, 256, 0, stream>>>(kvb, ln_g, ln_b);
    // 5) kv projection: [3136,512]@[512,1024] -> kvp (k | v)
    gemm64<<<dim3(16, 49), 256, 0, stream>>>(kvb, kv_w, nullptr, kvp, 3136, 1024, 512);
    // 6) q projection: [12544,512]@[512,512] -> qbuf
    gemm64<<<dim3(8, 196), 256, 0, stream>>>(x, q_w, nullptr, qbuf, 12544, 512, 512);
    // 7) attention v4 (LDS-staged, 2-wave KV split, no VGPR clamp) -> scr
    attn4<<<dim3(49, 8, 4), 128, 0, stream>>>(qbuf, kvp, scr);
    // 8) output projection (+bias): [12544,512]@[512,512] -> out
    gemm64<<<dim3(8, 196), 256, 0, stream>>>(scr, pj_w, pj_b, out, 12544, 512, 512);
}